// Round 3
// baseline (207.100 us; speedup 1.0000x reference)
//
#include <hip/hip_runtime.h>
#include <hip/hip_bf16.h>

// Problem: B=2, C=64, H=W=96 -> M=N=9216
//   scores[b,m,n] = sum_c yi[b,c,m]*pi[b,c,n] ; weight = softmax over m
//   out[b,c,n]    = sum_m yi[b,c,m]*weight[b,m,n]
// == flash attention with Q=pi (queries n), K=V=yi (keys m), head dim 64.
//
// R3: LDS data-path was the bottleneck (every wave read the full 16KB K-tile
// for only 16 query columns; ~130us of LDS-pipe cycles per CU).
//  (1) 32 n per wave: K-frag reads amortized over 2x MFMAs; V-frag read once
//      for both halves (both halves' P kept live in p_sm).
//  (2) prepass kernel bakes bf16 hi/lo conversion + transpose + XOR-swizzle
//      into global layout -> staging is pure global_load_lds width=16
//      (no ds_write, no VALU, no redundant per-block conversion).
//  (3) double-buffered K/V: stage(t+1) issued before compute(t); ONE barrier
//      per tile (barrier's vmcnt drain publishes the staged tile).

#define CC 64
#define MM 9216
#define BB 2
#define WAVES 6
#define NPW 32                 // query columns per wave
#define NBLK (WAVES * NPW)     // 192
#define NBX (MM / NBLK)        // 48
#define MTILE 64
#define NT (MM / MTILE)        // 144

typedef __bf16 bf16x8 __attribute__((ext_vector_type(8)));
typedef __bf16 bf16x4 __attribute__((ext_vector_type(4)));
typedef float f32x4 __attribute__((ext_vector_type(4)));

// row-XOR swizzle on 8-element groups (same as R2, verified conflict-free)
__device__ __forceinline__ int swz(int r) { return ((r >> 1) ^ (r >> 4)) & 7; }

__device__ __forceinline__ void gld16(const void* gsrc, void* ldst) {
    __builtin_amdgcn_global_load_lds(
        (const __attribute__((address_space(1))) void*)gsrc,
        (__attribute__((address_space(3))) void*)ldst, 16, 0, 0);
}

// ---------------- prepass: bake conversion + transpose + swizzle ----------------
// kt_hi/kt_lo[b][m][c ^ (swz(m&63)<<3)]  (m-major: one 8KB contiguous block/tile)
// vt[b][c][t*64 + ((m&63) ^ (swz(c)<<3))]
__global__ __launch_bounds__(256)
void prepass(const float* __restrict__ yi, __bf16* __restrict__ kt_hi,
             __bf16* __restrict__ kt_lo, __bf16* __restrict__ vt)
{
    const int t = blockIdx.x;     // key tile 0..143
    const int b = blockIdx.y;
    const int tid = threadIdx.x;  // 256
    const float* src = yi + (size_t)b * CC * MM;

    // kt tasks: m = tsk&63 (lane-coalesced), g = c-group of 8
    for (int tsk = tid; tsk < 512; tsk += 256) {
        const int m = tsk & 63, g = tsk >> 6;
        const int m_abs = t * 64 + m;
        bf16x8 hh, ll;
        #pragma unroll
        for (int j = 0; j < 8; ++j) {
            const float f = src[(size_t)(g * 8 + j) * MM + m_abs];
            const __bf16 hi = (__bf16)f;
            hh[j] = hi;
            ll[j] = (__bf16)(f - (float)hi);
        }
        const size_t o = (size_t)(b * MM + m_abs) * 64 + ((g ^ swz(m)) << 3);
        *reinterpret_cast<bf16x8*>(kt_hi + o) = hh;
        *reinterpret_cast<bf16x8*>(kt_lo + o) = ll;
    }
    // vt tasks: c = tsk&63, gm = m-group of 8 (contiguous source reads)
    for (int tsk = tid; tsk < 512; tsk += 256) {
        const int c = tsk & 63, gm = tsk >> 6;
        const float* p = src + (size_t)c * MM + t * 64 + gm * 8;
        bf16x8 hh;
        #pragma unroll
        for (int j = 0; j < 8; ++j) hh[j] = (__bf16)p[j];
        *reinterpret_cast<bf16x8*>(
            vt + (size_t)(b * CC + c) * MM + t * 64 + ((gm ^ swz(c)) << 3)) = hh;
    }
}

// ---------------- main flash kernel ----------------
template<bool FINAL>
__global__ __launch_bounds__(WAVES * 64, 3)   // VGPR<=168 -> 3 waves/EU -> 2 blocks/CU (LDS-matched)
void attn_main(const __bf16* __restrict__ kt_hi, const __bf16* __restrict__ kt_lo,
               const __bf16* __restrict__ vt, const float* __restrict__ pi,
               float* __restrict__ out, float* __restrict__ opart,
               float* __restrict__ mlpart, const int nsplits)
{
    __shared__ __align__(16) __bf16 k_hi[2][MTILE][64];   // 16KB (double-buffered)
    __shared__ __align__(16) __bf16 k_lo[2][MTILE][64];   // 16KB
    __shared__ __align__(16) __bf16 v_sm[2][CC][64];      // 16KB
    __shared__ __align__(16) __bf16 p_sm[WAVES][2][16][64]; // 24KB (both halves live)

    const int tid  = threadIdx.x;
    const int lane = tid & 63;
    const int wave = tid >> 6;     // 0..5
    const int ln   = lane & 15;
    const int lg   = lane >> 4;    // 0..3

    const int b     = blockIdx.z;
    const int split = blockIdx.y;
    const int tpb   = NT / nsplits;
    const int t0s   = split * tpb;
    const int n0    = blockIdx.x * NBLK + wave * NPW;   // this wave's 32 columns

    // ---- Q fragments (hi/lo split), 2 halves, loaded once ----
    bf16x8 qh[2][2], ql[2][2];
    #pragma unroll
    for (int h = 0; h < 2; ++h) {
        const float* qb = pi + (size_t)b * CC * MM + n0 + h * 16 + ln;
        #pragma unroll
        for (int ks = 0; ks < 2; ++ks)
            #pragma unroll
            for (int j = 0; j < 8; ++j) {
                const float f = qb[(size_t)(ks * 32 + lg * 8 + j) * MM];
                const __bf16 hi = (__bf16)f;
                qh[h][ks][j] = hi;
                ql[h][ks][j] = (__bf16)(f - (float)hi);
            }
    }

    f32x4 o[2][4];
    #pragma unroll
    for (int h = 0; h < 2; ++h)
        #pragma unroll
        for (int ct = 0; ct < 4; ++ct) o[h][ct] = (f32x4){0.f, 0.f, 0.f, 0.f};
    float run_max[2] = {-INFINITY, -INFINITY};
    float run_l[2]   = {0.f, 0.f};

    // ---- async staging: 24 x 1KB chunks, 4 per wave, linear LDS dest ----
    auto stage = [&](int buf, int t) {
        const size_t kbase = (size_t)(b * MM + t * 64) * 64;   // elements
        #pragma unroll
        for (int q = 0; q < 4; ++q) {
            const int ch = wave * 4 + q;        // wave-uniform
            if (ch < 8) {
                gld16(kt_hi + kbase + ch * 512 + lane * 8,
                      (char*)(&k_hi[buf][0][0]) + ch * 1024);
            } else if (ch < 16) {
                const int j = ch - 8;
                gld16(kt_lo + kbase + j * 512 + lane * 8,
                      (char*)(&k_lo[buf][0][0]) + j * 1024);
            } else {
                const int j = ch - 16;
                const int c = j * 8 + (lane >> 3);
                gld16(vt + (size_t)(b * CC + c) * MM + t * 64 + (lane & 7) * 8,
                      (char*)(&v_sm[buf][0][0]) + j * 1024);
            }
        }
    };

    int buf = 0;
    stage(0, t0s);
    __syncthreads();   // vmcnt drained -> buf0 ready

    for (int it = 0; it < tpb; ++it) {
        if (it + 1 < tpb) stage(buf ^ 1, t0s + it + 1);   // issue early, lands under compute

        // ---- QK^T: K-frag read once, used by both halves (6 MFMAs each) ----
        f32x4 s[2][4];
        #pragma unroll
        for (int h = 0; h < 2; ++h)
            #pragma unroll
            for (int mt = 0; mt < 4; ++mt) s[h][mt] = (f32x4){0.f, 0.f, 0.f, 0.f};
        #pragma unroll
        for (int ks = 0; ks < 2; ++ks) {
            #pragma unroll
            for (int mt = 0; mt < 4; ++mt) {
                const int col = (ks * 32 + lg * 8) ^ (((ln >> 1) ^ mt) << 3);
                const bf16x8 ah = *reinterpret_cast<const bf16x8*>(&k_hi[buf][mt * 16 + ln][col]);
                const bf16x8 al = *reinterpret_cast<const bf16x8*>(&k_lo[buf][mt * 16 + ln][col]);
                #pragma unroll
                for (int h = 0; h < 2; ++h) {
                    s[h][mt] = __builtin_amdgcn_mfma_f32_16x16x32_bf16(ah, qh[h][ks], s[h][mt], 0, 0, 0);
                    s[h][mt] = __builtin_amdgcn_mfma_f32_16x16x32_bf16(ah, ql[h][ks], s[h][mt], 0, 0, 0);
                    s[h][mt] = __builtin_amdgcn_mfma_f32_16x16x32_bf16(al, qh[h][ks], s[h][mt], 0, 0, 0);
                }
            }
        }

        // ---- online softmax per half; write P to this wave's slot ----
        #pragma unroll
        for (int h = 0; h < 2; ++h) {
            float tmax = -INFINITY;
            #pragma unroll
            for (int mt = 0; mt < 4; ++mt)
                #pragma unroll
                for (int r = 0; r < 4; ++r) tmax = fmaxf(tmax, s[h][mt][r]);
            tmax = fmaxf(tmax, __shfl_xor(tmax, 16));
            tmax = fmaxf(tmax, __shfl_xor(tmax, 32));

            const float mnew = fmaxf(run_max[h], tmax);
            const float corr = __expf(run_max[h] - mnew);

            float psum = 0.f;
            #pragma unroll
            for (int mt = 0; mt < 4; ++mt) {
                bf16x4 pp;
                #pragma unroll
                for (int r = 0; r < 4; ++r) {
                    const float pv = __expf(s[h][mt][r] - mnew);
                    psum += pv;
                    pp[r] = (__bf16)pv;
                }
                *reinterpret_cast<bf16x4*>(
                    &p_sm[wave][h][ln][(mt * 16 + lg * 4) ^ ((ln >> 1) << 3)]) = pp;
            }
            psum += __shfl_xor(psum, 16);
            psum += __shfl_xor(psum, 32);
            run_l[h]   = run_l[h] * corr + psum;
            run_max[h] = mnew;
            #pragma unroll
            for (int ct = 0; ct < 4; ++ct) o[h][ct] *= corr;
        }

        // ---- PV: V-frag read ONCE, feeds both halves ----
        // same-wave LDS write->read on p_sm: in-order, no barrier needed
        #pragma unroll
        for (int ks = 0; ks < 2; ++ks) {
            const int pcol = (ks * 32 + lg * 8) ^ ((ln >> 1) << 3);
            const bf16x8 bp0 = *reinterpret_cast<const bf16x8*>(&p_sm[wave][0][ln][pcol]);
            const bf16x8 bp1 = *reinterpret_cast<const bf16x8*>(&p_sm[wave][1][ln][pcol]);
            #pragma unroll
            for (int ct = 0; ct < 4; ++ct) {
                const int col = (ks * 32 + lg * 8) ^ (((ln >> 1) ^ ct) << 3);
                const bf16x8 av = *reinterpret_cast<const bf16x8*>(&v_sm[buf][ct * 16 + ln][col]);
                o[0][ct] = __builtin_amdgcn_mfma_f32_16x16x32_bf16(av, bp0, o[0][ct], 0, 0, 0);
                o[1][ct] = __builtin_amdgcn_mfma_f32_16x16x32_bf16(av, bp1, o[1][ct], 0, 0, 0);
            }
        }

        __syncthreads();   // readers of buf done; vmcnt drained -> buf^1 ready
        buf ^= 1;
    }

    // ---- epilogue ----
    #pragma unroll
    for (int h = 0; h < 2; ++h) {
        const int n_g = n0 + h * 16 + ln;
        if (FINAL) {
            const float inv = 1.f / run_l[h];
            #pragma unroll
            for (int ct = 0; ct < 4; ++ct)
                #pragma unroll
                for (int r = 0; r < 4; ++r) {
                    const int c = ct * 16 + lg * 4 + r;
                    out[((size_t)b * CC + c) * MM + n_g] = o[h][ct][r] * inv;
                }
        } else {
            const size_t pbase = (size_t)(b * nsplits + split) * CC * MM;
            #pragma unroll
            for (int ct = 0; ct < 4; ++ct)
                #pragma unroll
                for (int r = 0; r < 4; ++r) {
                    const int c = ct * 16 + lg * 4 + r;
                    opart[pbase + (size_t)c * MM + n_g] = o[h][ct][r];
                }
            if (lg == 0) {
                const size_t mb = ((size_t)(b * nsplits + split) * MM + n_g) * 2;
                mlpart[mb]     = run_max[h];
                mlpart[mb + 1] = run_l[h];
            }
        }
    }
}

// out = sum_s O_s * e^{m_s - M} / sum_s l_s * e^{m_s - M}
template<int S>
__global__ __launch_bounds__(256)
void attn_reduce(const float* __restrict__ opart, const float* __restrict__ mlpart,
                 float* __restrict__ out)
{
    const int gid = blockIdx.x * 256 + threadIdx.x;
    if (gid >= BB * CC * MM) return;
    const int n  = gid % MM;
    const int bc = gid / MM;
    const int b  = bc / CC;
    const int c  = bc - b * CC;

    float ms[S], ls[S];
    float Mx = -INFINITY;
    #pragma unroll
    for (int s = 0; s < S; ++s) {
        const size_t mb = ((size_t)(b * S + s) * MM + n) * 2;
        ms[s] = mlpart[mb];
        ls[s] = mlpart[mb + 1];
        Mx = fmaxf(Mx, ms[s]);
    }
    float L = 0.f;
    #pragma unroll
    for (int s = 0; s < S; ++s) {
        ms[s] = __expf(ms[s] - Mx);
        L += ls[s] * ms[s];
    }
    float acc = 0.f;
    #pragma unroll
    for (int s = 0; s < S; ++s)
        acc += opart[((size_t)(b * S + s) * CC + c) * MM + n] * ms[s];
    out[gid] = acc / L;
}

extern "C" void kernel_launch(void* const* d_in, const int* in_sizes, int n_in,
                              void* d_out, int out_size, void* d_ws, size_t ws_size,
                              hipStream_t stream) {
    const float* yi = (const float*)d_in[0];   // feature_yi (K = V)
    const float* pi = (const float*)d_in[1];   // feature_pi (Q)
    float* out = (float*)d_out;

    const size_t kelems = (size_t)BB * MM * 64;              // kt_hi / kt_lo elements
    const size_t velems = (size_t)BB * CC * MM;              // vt elements
    const size_t preB   = (kelems * 2 + velems) * 2;         // ~7.1 MB
    auto need = [&](int s) -> size_t {
        return preB + (size_t)BB * s * CC * MM * 4 + (size_t)BB * s * MM * 8;
    };

    int S = 1;
    if (d_ws) {
        if (ws_size >= need(16))     S = 16;  // 1536 blocks = 6/CU, 3 even rounds of 2
        else if (ws_size >= need(8)) S = 8;   // 768 blocks
        else if (ws_size >= need(4)) S = 4;
        else if (ws_size >= need(2)) S = 2;
    }
    if (S == 1) return;  // ws always >= need(2) (~16MB) in this harness; R2 ran S=8

    __bf16* kt_hi = (__bf16*)d_ws;
    __bf16* kt_lo = kt_hi + kelems;
    __bf16* vt    = kt_lo + kelems;
    float* opart  = (float*)(vt + velems);
    float* ml     = opart + (size_t)BB * S * CC * MM;

    prepass<<<dim3(NT, BB), dim3(256), 0, stream>>>(yi, kt_hi, kt_lo, vt);

    attn_main<false><<<dim3(NBX, S, BB), dim3(WAVES * 64), 0, stream>>>(
        kt_hi, kt_lo, vt, pi, out, opart, ml, S);

    const int total = BB * CC * MM;
    const dim3 rg((total + 255) / 256), rb(256);
    if (S == 16)     attn_reduce<16><<<rg, rb, 0, stream>>>(opart, ml, out);
    else if (S == 8) attn_reduce<8><<<rg, rb, 0, stream>>>(opart, ml, out);
    else if (S == 4) attn_reduce<4><<<rg, rb, 0, stream>>>(opart, ml, out);
    else             attn_reduce<2><<<rg, rb, 0, stream>>>(opart, ml, out);
}